// Round 12
// baseline (124.355 us; speedup 1.0000x reference)
//
#include <hip/hip_runtime.h>
#include <math.h>

// Problem constants: B=4, N=65536, IN=2, OUT=512, C=64, H=32, W=32, W0=30
#define SIREN_W0 30.0f

typedef float f32x4 __attribute__((ext_vector_type(4)));
typedef float f32x2 __attribute__((ext_vector_type(2)));

// ---------------------------------------------------------------------------
// Kernel 1 (unchanged R4): combined[pos][o] = dots + b_shift[o] + b_vshift[o]
// Both reference gathers use the SAME (iy,ix) -> one combined map suffices.
// ---------------------------------------------------------------------------
__global__ __launch_bounds__(256) void build_combined(
    const float* __restrict__ latent, const float* __restrict__ v,
    const float* __restrict__ W_shift, const float* __restrict__ b_shift,
    const float* __restrict__ W_vshift, const float* __restrict__ b_vshift,
    float* __restrict__ combined)
{
    __shared__ float featL[16][64];
    __shared__ float featV[16][64];
    const int pos0 = blockIdx.x * 16;
    const int b    = pos0 >> 10;
    const int rem  = pos0 & 1023;
    const int t    = threadIdx.x;

    const float* latBase = latent + (size_t)b * 65536 + rem;
    const float* vBase   = v      + (size_t)b * 65536 + rem;
#pragma unroll
    for (int k = 0; k < 4; ++k) {
        int e = t + k * 256;
        int c = e >> 4, p = e & 15;
        featL[p][c] = latBase[c * 1024 + p];
        featV[p][c] = vBase[c * 1024 + p];
    }
    __syncthreads();

    const int og = t & 127;
    const int pg = t >> 7;
    const int o0 = og * 4;
    const int p0 = pg * 8;

    float acc[8][4];
#pragma unroll
    for (int j = 0; j < 4; ++j) {
        float binit = b_shift[o0 + j] + b_vshift[o0 + j];
#pragma unroll
        for (int p = 0; p < 8; ++p) acc[p][j] = binit;
    }

    const f32x4* WS = (const f32x4*)(W_shift  + (size_t)o0 * 64);
    const f32x4* WV = (const f32x4*)(W_vshift + (size_t)o0 * 64);

#pragma unroll 4
    for (int c4 = 0; c4 < 16; ++c4) {
        f32x4 wS[4], wV[4];
#pragma unroll
        for (int j = 0; j < 4; ++j) {
            wS[j] = WS[j * 16 + c4];
            wV[j] = WV[j * 16 + c4];
        }
#pragma unroll
        for (int p = 0; p < 8; ++p) {
            f32x4 fL = *(const f32x4*)&featL[p0 + p][c4 * 4];
            f32x4 fV = *(const f32x4*)&featV[p0 + p][c4 * 4];
#pragma unroll
            for (int j = 0; j < 4; ++j) {
                acc[p][j] += fL.x * wS[j].x + fL.y * wS[j].y
                           + fL.z * wS[j].z + fL.w * wS[j].w
                           + fV.x * wV[j].x + fV.y * wV[j].y
                           + fV.z * wV[j].z + fV.w * wV[j].w;
            }
        }
    }

#pragma unroll
    for (int p = 0; p < 8; ++p) {
        f32x4 r = { acc[p][0], acc[p][1], acc[p][2], acc[p][3] };
        *(f32x4*)(combined + (size_t)(pos0 + p0 + p) * 512 + o0) = r;
    }
}

// ---------------------------------------------------------------------------
// Kernel 2: R4 body (32 threads/point, 4 chunks/thread, __sinf, nt stores,
// XCD swizzle) with ONE change: W_lin/b_lin served from LDS (6 KB, staged
// once per block). Removes 3 of 4 global-read instructions per k-iteration
// (~60% of per-CU L1 return bytes) from the TA path; LDS pipe absorbs them.
// Loop structure, point order, store pattern unchanged.
// ---------------------------------------------------------------------------
__global__ __launch_bounds__(256) void siren_out(
    const float* __restrict__ x, const float* __restrict__ W_lin,
    const float* __restrict__ b_lin, const float* __restrict__ combined,
    float* __restrict__ out)
{
    __shared__ f32x4 sWA[128];   // W_lin rows 2c   (o = 4c+0,1 pair layout)
    __shared__ f32x4 sWB[128];   // W_lin rows 2c+1
    __shared__ f32x4 sB [128];   // b_lin

    const int t = threadIdx.x;
    {
        const f32x4* Wl4 = (const f32x4*)W_lin;
        if (t < 128) {
            sWA[t] = Wl4[2 * t];
            sWB[t] = Wl4[2 * t + 1];
        } else {
            sB[t - 128] = ((const f32x4*)b_lin)[t - 128];
        }
    }
    __syncthreads();

    const int bid = blockIdx.x;
    const int xcd = bid & 7;
    const int idx = bid >> 3;
    const int pb  = ((xcd >> 1) << 13) + ((xcd & 1) << 12) + idx;

    const int tid   = pb * 256 + t;
    const int point = tid >> 5;
    const int lane  = tid & 31;
    const int b     = point >> 16;

    const f32x2 xv = *(const f32x2*)(x + (size_t)point * 2);

    const f32x4 wl = *(const f32x4*)W_lin;
    const f32x2 bl = *(const f32x2*)b_lin;
    const float h0 = xv.x * wl.x + xv.y * wl.y + bl.x;
    const float h1 = xv.x * wl.z + xv.y * wl.w + bl.y;

    const float fx = (h0 + 1.0f) * 0.5f * 31.0f;
    const float fy = (h1 + 1.0f) * 0.5f * 31.0f;
    int ix = (int)rintf(fx); ix = ix < 0 ? 0 : (ix > 31 ? 31 : ix);
    int iy = (int)rintf(fy); iy = iy < 0 ? 0 : (iy > 31 ? 31 : iy);

    const f32x4* crow =
        (const f32x4*)(combined + (size_t)(((b << 5) + iy) * 32 + ix) * 512);
    f32x4* orow = ((f32x4*)out) + (size_t)point * 128;

#pragma unroll
    for (int k = 0; k < 4; ++k) {
        const int chunk = lane + k * 32;
        const f32x4 c4 = crow[chunk];
        const f32x4 wA = sWA[chunk];
        const f32x4 wB = sWB[chunk];
        const f32x4 bb = sB[chunk];

        f32x4 r;
        r.x = __sinf(SIREN_W0 * (xv.x * wA.x + xv.y * wA.y + bb.x + c4.x));
        r.y = __sinf(SIREN_W0 * (xv.x * wA.z + xv.y * wA.w + bb.y + c4.y));
        r.z = __sinf(SIREN_W0 * (xv.x * wB.x + xv.y * wB.y + bb.z + c4.z));
        r.w = __sinf(SIREN_W0 * (xv.x * wB.z + xv.y * wB.w + bb.w + c4.w));

        __builtin_nontemporal_store(r, orow + chunk);
    }
}

extern "C" void kernel_launch(void* const* d_in, const int* in_sizes, int n_in,
                              void* d_out, int out_size, void* d_ws, size_t ws_size,
                              hipStream_t stream) {
    const float* x        = (const float*)d_in[0];
    const float* latent   = (const float*)d_in[1];
    const float* v        = (const float*)d_in[2];
    const float* W_lin    = (const float*)d_in[3];
    const float* b_lin    = (const float*)d_in[4];
    const float* W_shift  = (const float*)d_in[5];
    const float* b_shift  = (const float*)d_in[6];
    const float* W_vshift = (const float*)d_in[7];
    const float* b_vshift = (const float*)d_in[8];
    float* out      = (float*)d_out;
    float* combined = (float*)d_ws;   // 8 MiB of d_ws

    build_combined<<<256, 256, 0, stream>>>(latent, v, W_shift, b_shift,
                                            W_vshift, b_vshift, combined);

    siren_out<<<32768, 256, 0, stream>>>(x, W_lin, b_lin, combined, out);
}

// Round 13
// 114.786 us; speedup vs baseline: 1.0834x; 1.0834x over previous
//
#include <hip/hip_runtime.h>
#include <math.h>

// Problem constants: B=4, N=65536, IN=2, OUT=512, C=64, H=32, W=32, W0=30
#define SIREN_W0 30.0f

typedef float f32x4 __attribute__((ext_vector_type(4)));
typedef float f32x2 __attribute__((ext_vector_type(2)));

// ---------------------------------------------------------------------------
// Kernel 1 (R4): combined[pos][o] = dots + b_shift[o] + b_vshift[o]
// Both reference gathers use the SAME (iy,ix) -> one combined map suffices.
// ---------------------------------------------------------------------------
__global__ __launch_bounds__(256) void build_combined(
    const float* __restrict__ latent, const float* __restrict__ v,
    const float* __restrict__ W_shift, const float* __restrict__ b_shift,
    const float* __restrict__ W_vshift, const float* __restrict__ b_vshift,
    float* __restrict__ combined)
{
    __shared__ float featL[16][64];
    __shared__ float featV[16][64];
    const int pos0 = blockIdx.x * 16;
    const int b    = pos0 >> 10;
    const int rem  = pos0 & 1023;
    const int t    = threadIdx.x;

    const float* latBase = latent + (size_t)b * 65536 + rem;
    const float* vBase   = v      + (size_t)b * 65536 + rem;
#pragma unroll
    for (int k = 0; k < 4; ++k) {
        int e = t + k * 256;
        int c = e >> 4, p = e & 15;
        featL[p][c] = latBase[c * 1024 + p];
        featV[p][c] = vBase[c * 1024 + p];
    }
    __syncthreads();

    const int og = t & 127;
    const int pg = t >> 7;
    const int o0 = og * 4;
    const int p0 = pg * 8;

    float acc[8][4];
#pragma unroll
    for (int j = 0; j < 4; ++j) {
        float binit = b_shift[o0 + j] + b_vshift[o0 + j];
#pragma unroll
        for (int p = 0; p < 8; ++p) acc[p][j] = binit;
    }

    const f32x4* WS = (const f32x4*)(W_shift  + (size_t)o0 * 64);
    const f32x4* WV = (const f32x4*)(W_vshift + (size_t)o0 * 64);

#pragma unroll 4
    for (int c4 = 0; c4 < 16; ++c4) {
        f32x4 wS[4], wV[4];
#pragma unroll
        for (int j = 0; j < 4; ++j) {
            wS[j] = WS[j * 16 + c4];
            wV[j] = WV[j * 16 + c4];
        }
#pragma unroll
        for (int p = 0; p < 8; ++p) {
            f32x4 fL = *(const f32x4*)&featL[p0 + p][c4 * 4];
            f32x4 fV = *(const f32x4*)&featV[p0 + p][c4 * 4];
#pragma unroll
            for (int j = 0; j < 4; ++j) {
                acc[p][j] += fL.x * wS[j].x + fL.y * wS[j].y
                           + fL.z * wS[j].z + fL.w * wS[j].w
                           + fV.x * wV[j].x + fV.y * wV[j].y
                           + fV.z * wV[j].z + fV.w * wV[j].w;
            }
        }
    }

#pragma unroll
    for (int p = 0; p < 8; ++p) {
        f32x4 r = { acc[p][0], acc[p][1], acc[p][2], acc[p][3] };
        *(f32x4*)(combined + (size_t)(pos0 + p0 + p) * 512 + o0) = r;
    }
}

// ---------------------------------------------------------------------------
// Kernel 2: the proven 114.6us configuration (R4 body, nt stores, XCD
// swizzle). 32 threads/point, 4 chunks/thread; weights from global (L1-hit).
// Best of 11 tested variants; every single-variable deviation regressed or
// was neutral. NT stores mandatory (removal costs +57%, R6).
// ---------------------------------------------------------------------------
__global__ __launch_bounds__(256) void siren_out(
    const float* __restrict__ x, const float* __restrict__ W_lin,
    const float* __restrict__ b_lin, const float* __restrict__ combined,
    float* __restrict__ out)
{
    const int bid = blockIdx.x;
    const int xcd = bid & 7;
    const int idx = bid >> 3;
    const int pb  = ((xcd >> 1) << 13) + ((xcd & 1) << 12) + idx;

    const int tid   = pb * 256 + threadIdx.x;
    const int point = tid >> 5;
    const int lane  = tid & 31;
    const int b     = point >> 16;

    const f32x2 xv = *(const f32x2*)(x + (size_t)point * 2);

    const f32x4 wl = *(const f32x4*)W_lin;
    const f32x2 bl = *(const f32x2*)b_lin;
    const float h0 = xv.x * wl.x + xv.y * wl.y + bl.x;
    const float h1 = xv.x * wl.z + xv.y * wl.w + bl.y;

    const float fx = (h0 + 1.0f) * 0.5f * 31.0f;
    const float fy = (h1 + 1.0f) * 0.5f * 31.0f;
    int ix = (int)rintf(fx); ix = ix < 0 ? 0 : (ix > 31 ? 31 : ix);
    int iy = (int)rintf(fy); iy = iy < 0 ? 0 : (iy > 31 ? 31 : iy);

    const f32x4* crow =
        (const f32x4*)(combined + (size_t)(((b << 5) + iy) * 32 + ix) * 512);
    const f32x4* Wl4 = (const f32x4*)W_lin;
    const f32x4* Bl4 = (const f32x4*)b_lin;
    f32x4* orow = ((f32x4*)out) + (size_t)point * 128;

#pragma unroll
    for (int k = 0; k < 4; ++k) {
        const int chunk = lane + k * 32;
        const f32x4 c4 = crow[chunk];
        const f32x4 wA = Wl4[chunk * 2];
        const f32x4 wB = Wl4[chunk * 2 + 1];
        const f32x4 bb = Bl4[chunk];

        f32x4 r;
        r.x = __sinf(SIREN_W0 * (xv.x * wA.x + xv.y * wA.y + bb.x + c4.x));
        r.y = __sinf(SIREN_W0 * (xv.x * wA.z + xv.y * wA.w + bb.y + c4.y));
        r.z = __sinf(SIREN_W0 * (xv.x * wB.x + xv.y * wB.y + bb.z + c4.z));
        r.w = __sinf(SIREN_W0 * (xv.x * wB.z + xv.y * wB.w + bb.w + c4.w));

        __builtin_nontemporal_store(r, orow + chunk);
    }
}

extern "C" void kernel_launch(void* const* d_in, const int* in_sizes, int n_in,
                              void* d_out, int out_size, void* d_ws, size_t ws_size,
                              hipStream_t stream) {
    const float* x        = (const float*)d_in[0];
    const float* latent   = (const float*)d_in[1];
    const float* v        = (const float*)d_in[2];
    const float* W_lin    = (const float*)d_in[3];
    const float* b_lin    = (const float*)d_in[4];
    const float* W_shift  = (const float*)d_in[5];
    const float* b_shift  = (const float*)d_in[6];
    const float* W_vshift = (const float*)d_in[7];
    const float* b_vshift = (const float*)d_in[8];
    float* out      = (float*)d_out;
    float* combined = (float*)d_ws;   // 8 MiB of d_ws

    build_combined<<<256, 256, 0, stream>>>(latent, v, W_shift, b_shift,
                                            W_vshift, b_vshift, combined);

    // 48 KB dynamic-LDS ballast: caps occupancy at 3 blocks/CU (neutral but
    // measured marginally best, 114.6us). Body identical to the R4 optimum.
    siren_out<<<32768, 256, 49152, stream>>>(x, W_lin, b_lin, combined, out);
}